// Round 1
// 126.479 us; speedup vs baseline: 1.1021x; 1.1021x over previous
//
#include <hip/hip_runtime.h>

// phi = exp(-d2/(2*ls^2)) = exp2(-S2*d2), S2 = 1/(2*ls^2*ln2) = 8.014973
// Expanded: exp2(2*S2*(x.c) - S2*|x|^2 - S2*|c|^2)
//   per-center pack a = (K2*cx, K2*cy, K2*cz, -S2*|c|^2), K2 = 2*S2
//   per-lane PX = -S2*|x|^2
#define S2 8.014973f
#define K2 16.029946f
#define WAVES 8    // waves per block, each owns one center chunk
#define CSPLIT 4   // center-split across blocks (finer grid -> CU balance)

typedef float f2 __attribute__((ext_vector_type(2)));

__global__ void rbf_prep_kernel(const float* __restrict__ centers,
                                const float* __restrict__ cu,
                                const float* __restrict__ cv,
                                const float* __restrict__ cw,
                                float4* __restrict__ cpack, int M) {
    int m = blockIdx.x * 256 + threadIdx.x;
    if (m < M) {
        float cx = centers[3 * m + 0];
        float cy = centers[3 * m + 1];
        float cz = centers[3 * m + 2];
        float4 a, b;
        a.x = K2 * cx;
        a.y = K2 * cy;
        a.z = K2 * cz;
        a.w = -S2 * (cx * cx + cy * cy + cz * cz);
        b.x = cu[m];
        b.y = cv[m];
        b.z = cw[m];
        b.w = 0.f;
        cpack[2 * m + 0] = a;
        cpack[2 * m + 1] = b;
    }
}

// Block = 512 threads = 8 waves; block owns 128 points (2/lane as f2 halves).
// Centers are split CSPLIT ways ACROSS blocks and WAVES ways within a block:
// 32 global chunks of ~106 centers. grid = 782*4 = 3128 blocks = 12.2/CU
// (vs 782 = 3.05/CU before: 14 CUs got a 4th block -> 33% straggler tail;
// now tail ~7% and residency stays at 32 waves/CU for the whole main phase).
// Each block LDS-reduces its 8 waves, then atomically adds its partial into
// out (out pre-zeroed by hipMemsetAsync; 4 atomics per output element).
__global__ __launch_bounds__(512) void rbf_main_kernel(
    const float* __restrict__ x, const float4* __restrict__ cpack,
    float* __restrict__ out, int N, int M) {
    __shared__ float acc[WAVES][128][3];

    const int tid = threadIdx.x;
    const int lane = tid & 63;
    const int wave = __builtin_amdgcn_readfirstlane(tid >> 6);  // wave-uniform
    const int cs = blockIdx.x & (CSPLIT - 1);
    const int pbase = (blockIdx.x / CSPLIT) * 128;
    const int p0 = pbase + lane;
    const int p1 = pbase + 64 + lane;

    float x00 = 0.f, x01 = 0.f, x02 = 0.f;
    float x10 = 0.f, x11 = 0.f, x12 = 0.f;
    if (p0 < N) {
        x00 = x[3 * p0 + 0];
        x01 = x[3 * p0 + 1];
        x02 = x[3 * p0 + 2];
    }
    if (p1 < N) {
        x10 = x[3 * p1 + 0];
        x11 = x[3 * p1 + 1];
        x12 = x[3 * p1 + 2];
    }

    const f2 X = {x00, x10};
    const f2 Y = {x01, x11};
    const f2 Z = {x02, x12};
    const f2 PX = {-S2 * (x00 * x00 + x01 * x01 + x02 * x02),
                   -S2 * (x10 * x10 + x11 * x11 + x12 * x12)};

    // global chunk id: wave-uniform -> scalar loads of cpack
    const int g = cs * WAVES + wave;
    const int per = (M + WAVES * CSPLIT - 1) / (WAVES * CSPLIT);
    const int jb = g * per;
    int je = jb + per;
    if (je > M) je = M;

    f2 au = {0.f, 0.f}, av = {0.f, 0.f}, aw = {0.f, 0.f};

#pragma unroll 8
    for (int j = jb; j < je; ++j) {
        const float4 a = cpack[2 * j + 0];  // uniform addr -> s_load
        const float4 b = cpack[2 * j + 1];
        f2 e = PX + a.w;
        e += Z * a.z;
        e += Y * a.y;
        e += X * a.x;
        f2 phi;
        phi.x = __builtin_amdgcn_exp2f(e.x);
        phi.y = __builtin_amdgcn_exp2f(e.y);
        au += phi * b.x;
        av += phi * b.y;
        aw += phi * b.z;
    }

    // Fold base field x*(1-||x||) into global chunk 0's partials (once/point).
    if (g == 0) {
        float g0 = 1.f - sqrtf(x00 * x00 + x01 * x01 + x02 * x02);
        au.x += x00 * g0;
        av.x += x01 * g0;
        aw.x += x02 * g0;
        float g1 = 1.f - sqrtf(x10 * x10 + x11 * x11 + x12 * x12);
        au.y += x10 * g1;
        av.y += x11 * g1;
        aw.y += x12 * g1;
    }

    acc[wave][lane][0] = au.x;
    acc[wave][lane][1] = av.x;
    acc[wave][lane][2] = aw.x;
    acc[wave][64 + lane][0] = au.y;
    acc[wave][64 + lane][1] = av.y;
    acc[wave][64 + lane][2] = aw.y;
    __syncthreads();

    // 384 outputs per block; addresses k*384+tid are stride-1 -> conflict-free
    if (tid < 384) {
        const int gi = pbase * 3 + tid;
        if (gi < 3 * N) {
            const float* af = &acc[0][0][0];
            float s = 0.f;
#pragma unroll
            for (int k = 0; k < WAVES; ++k) s += af[k * 384 + tid];
            unsafeAtomicAdd(&out[gi], s);  // HW global_atomic_add_f32
        }
    }
}

extern "C" void kernel_launch(void* const* d_in, const int* in_sizes, int n_in,
                              void* d_out, int out_size, void* d_ws,
                              size_t ws_size, hipStream_t stream) {
    const float* x = (const float*)d_in[0];
    const float* centers = (const float*)d_in[1];
    const float* cu = (const float*)d_in[2];
    const float* cv = (const float*)d_in[3];
    const float* cw = (const float*)d_in[4];
    const int N = in_sizes[0] / 3;
    const int M = in_sizes[1] / 3;
    float4* cpack = (float4*)d_ws;
    float* out = (float*)d_out;

    hipLaunchKernelGGL(rbf_prep_kernel, dim3((M + 255) / 256), dim3(256), 0,
                       stream, centers, cu, cv, cw, cpack, M);
    hipMemsetAsync(d_out, 0, (size_t)out_size, stream);
    const int pt = (N + 127) / 128;
    hipLaunchKernelGGL(rbf_main_kernel, dim3(pt * CSPLIT), dim3(512), 0,
                       stream, x, cpack, out, N, M);
}